// Round 15
// baseline (1059.521 us; speedup 1.0000x reference)
//
#include <hip/hip_runtime.h>

#define HH   6
#define NN   343
#define BB   512
#define DIMC 192
#define MM   (BB*NN)      // 175616

// workspace offsets (bytes)
#define OFF_TABLE 0                        // [2197][8] f32
#define OFF_R     70400                    // [6][343][352] f32  (exp(rpb-26), zero tail)
#define OFF_MB    2968064                  // [64*343][16] u32   (bit-packed mask, 32x32-reg order)
#define OFF_QB    4372992                  // [M][192] bf16 (normalized * scale * log2e)
#define OFF_KB    (OFF_QB + 67436544)      // [M][192] bf16 (normalized)
#define OFF_VB    (OFF_KB + 67436544)
#define OFF_CROSS (OFF_VB + 67436544)
#define OFF_WB    (OFF_CROSS + 67436544)   // [1344][192] bf16: qkv1(576), qkv2(576), proj(192)
// end = 274,635,264 bytes

typedef __bf16 bf16x8 __attribute__((ext_vector_type(8)));
typedef float  f32x4  __attribute__((ext_vector_type(4)));
typedef float  f32x16 __attribute__((ext_vector_type(16)));

__device__ __forceinline__ f32x4 mfma16(bf16x8 a, bf16x8 b, f32x4 c) {
    return __builtin_amdgcn_mfma_f32_16x16x32_bf16(a, b, c, 0, 0, 0);
}
__device__ __forceinline__ f32x16 mfma32(bf16x8 a, bf16x8 b, f32x16 c) {
    return __builtin_amdgcn_mfma_f32_32x32x16_bf16(a, b, c, 0, 0, 0);
}

__device__ __forceinline__ unsigned pack2(float a, float b) {
    union { __bf16 h[2]; unsigned u; } x;
    x.h[0] = (__bf16)a; x.h[1] = (__bf16)b;
    return x.u;
}
// swaps a[32:63] <-> b[0:31]
__device__ __forceinline__ void pl32_swap(unsigned &a, unsigned &b) {
    asm volatile("v_permlane32_swap_b32 %0, %1" : "+v"(a), "+v"(b));
}

// ---------------- K1: CPB MLP -> table[2197][8] ----------------
__global__ __launch_bounds__(256) void cpb_table_kernel(
    const float* __restrict__ rel_table, const float* __restrict__ w1,
    const float* __restrict__ b1, const float* __restrict__ w2,
    float* __restrict__ table)
{
    int i = blockIdx.x;
    int t = threadIdx.x;
    float t0 = rel_table[i*3+0], t1 = rel_table[i*3+1], t2 = rel_table[i*3+2];
    float acc[HH];
    #pragma unroll
    for (int h = 0; h < HH; h++) acc[h] = 0.f;
    for (int j = t; j < 512; j += 256) {
        float hv = w1[j*3+0]*t0 + w1[j*3+1]*t1 + w1[j*3+2]*t2 + b1[j];
        hv = fmaxf(hv, 0.f);
        #pragma unroll
        for (int h = 0; h < HH; h++) acc[h] += w2[h*512+j] * hv;
    }
    __shared__ float red[256*HH];
    #pragma unroll
    for (int h = 0; h < HH; h++) red[t*HH+h] = acc[h];
    __syncthreads();
    for (int s = 128; s > 0; s >>= 1) {
        if (t < s) {
            #pragma unroll
            for (int h = 0; h < HH; h++) red[t*HH+h] += red[(t+s)*HH+h];
        }
        __syncthreads();
    }
    if (t < HH) table[(size_t)i*8 + t] = red[t];
}

// ---------------- K2: R = exp(16*sigmoid(gather) - 26), [6][343][352] ----------------
__global__ __launch_bounds__(256) void r_kernel(
    const float* __restrict__ table, const int* __restrict__ rp_index,
    float* __restrict__ R)
{
    int id = blockIdx.x*256 + threadIdx.x;
    if (id >= HH*NN*352) return;
    int h   = id / (NN*352);
    int rem = id - h*(NN*352);
    int n   = rem / 352;
    int mc  = rem - n*352;
    float out = 0.f;
    if (mc < NN) {
        float v = table[(size_t)rp_index[n*NN+mc]*8 + h];
        float r = 16.f / (1.f + __expf(-v));
        out = __expf(r - 26.f);
    }
    R[id] = out;
}

// ---------------- K3: bit-pack mask for 32x32 reg order ----------------
__global__ __launch_bounds__(256) void mbits2_kernel(
    const float* __restrict__ mask, unsigned* __restrict__ mb)
{
    int id = blockIdx.x*256 + threadIdx.x;    // 64*343*2 threads
    if (id >= 64*NN*2) return;
    int hi  = id & 1;
    int row = id >> 1;                         // w*343 + n
    const float* mrow = mask + (size_t)row*NN;
    unsigned* out = mb + (size_t)row*16 + hi*8;
    #pragma unroll
    for (int wd = 0; wd < 6; wd++) {
        unsigned u = 0;
        #pragma unroll
        for (int p = 0; p < 32; p++) {
            int g = 32*wd + p;
            int ks = g >> 4, r = g & 15;
            int m = 32*ks + (r&3) + 8*(r>>2) + 4*hi;
            if (m < NN && mrow[m] > -50.f) u |= (1u << p);
        }
        out[wd] = u;
    }
    out[6] = 0u; out[7] = 0u;
}

// ---------------- K4: convert weights f32 -> bf16 (qkv1 | qkv2 | proj) ----------------
__global__ __launch_bounds__(256) void wcvt_kernel(
    const float* __restrict__ qkv1, const float* __restrict__ qkv2,
    const float* __restrict__ proj, __bf16* __restrict__ out)
{
    int i = blockIdx.x*256 + threadIdx.x;   // float4 index
    const int n1 = 110592/4, n2 = 221184/4, n3 = 258048/4;
    if (i >= n3) return;
    const float* src; int off;
    if (i < n1)      { src = qkv1; off = i; }
    else if (i < n2) { src = qkv2; off = i - n1; }
    else             { src = proj; off = i - n2; }
    float4 v = ((const float4*)src)[off];
    __bf16* d = out + (size_t)i*4;
    d[0] = (__bf16)v.x; d[1] = (__bf16)v.y; d[2] = (__bf16)v.z; d[3] = (__bf16)v.w;
}

// ---------------- GEMM v4: f32 A direct, bf16 W double-buffered in LDS, 2 phases ----------------
// norm: 0 = none, 1 = k-norm (1/|k|), 2 = q-norm (scale*log2e/|q|)
__global__ __launch_bounds__(256) void gemm_f32in(
    const float* __restrict__ A, const float* __restrict__ ls,
    const __bf16* __restrict__ W0, const float* __restrict__ bias0, int norm0, __bf16* __restrict__ D0,
    const __bf16* __restrict__ W1, const float* __restrict__ bias1, int norm1, __bf16* __restrict__ D1)
{
    __shared__ __bf16 Ws[2][192*40];   // 30720 B
    int m0 = blockIdx.x * 64;
    int t  = threadIdx.x;
    int wave = t >> 6, lane = t & 63, lr = lane & 15, lg = lane >> 4;
    int r = m0 + 16*wave + lr;

    // A row fragments, f32 -> bf16, kept in regs across phases
    bf16x8 afr[6];
    #pragma unroll
    for (int ks = 0; ks < 6; ks++) {
        const float* ap = A + (size_t)r*DIMC + 32*ks + 8*lg;
        float4 v0 = *(const float4*)ap;
        float4 v1 = *(const float4*)(ap + 4);
        bf16x8 f;
        f[0]=(__bf16)v0.x; f[1]=(__bf16)v0.y; f[2]=(__bf16)v0.z; f[3]=(__bf16)v0.w;
        f[4]=(__bf16)v1.x; f[5]=(__bf16)v1.y; f[6]=(__bf16)v1.z; f[7]=(__bf16)v1.w;
        afr[ks] = f;
    }

    #pragma unroll 1
    for (int phase = 0; phase < 2; phase++) {
        const __bf16* W    = phase ? W1 : W0;
        if (!W) break;
        const float* bias  = phase ? bias1 : bias0;
        int          nrm   = phase ? norm1 : norm0;
        __bf16*      D     = phase ? D1 : D0;
        f32x4 acc[12];
        #pragma unroll
        for (int i = 0; i < 12; i++) acc[i] = (f32x4){0.f,0.f,0.f,0.f};

        // stage chunk 0 into buf 0
        #pragma unroll
        for (int i = 0; i < 3; i++) {
            int c = t + 256*i;
            int row = c >> 2, cg = c & 3;
            uint4 v = *(const uint4*)(W + (size_t)row*DIMC + 8*cg);
            *(uint4*)&Ws[0][row*40 + 8*cg] = v;
        }

        #pragma unroll 1
        for (int ks = 0; ks < 6; ks++) {
            __syncthreads();
            // issue stage of chunk ks+1 into the other buffer (overlaps MFMAs below)
            if (ks < 5) {
                #pragma unroll
                for (int i = 0; i < 3; i++) {
                    int c = t + 256*i;
                    int row = c >> 2, cg = c & 3;
                    uint4 v = *(const uint4*)(W + (size_t)row*DIMC + 32*(ks+1) + 8*cg);
                    *(uint4*)&Ws[(ks+1)&1][row*40 + 8*cg] = v;
                }
            }
            const __bf16* Wb = Ws[ks&1];
            #pragma unroll
            for (int ct = 0; ct < 12; ct++) {
                bf16x8 bfrag = *(const bf16x8*)&Wb[(16*ct + lr)*40 + 8*lg];
                acc[ct] = mfma16(afr[ks], bfrag, acc[ct]);
            }
        }
        __syncthreads();   // protect buf reuse across phases

        if (bias) {
            #pragma unroll
            for (int ct = 0; ct < 12; ct++) {
                float bv = bias[16*ct + lr];
                #pragma unroll
                for (int reg = 0; reg < 4; reg++) acc[ct][reg] += bv;
            }
        }
        if (nrm) {
            #pragma unroll
            for (int h = 0; h < HH; h++) {
                float sc = 1.f;
                if (nrm == 2) sc = __expf(fminf(ls[h], 4.6051702f)) * 1.4426950408889634f;
                #pragma unroll
                for (int reg = 0; reg < 4; reg++) {
                    float ss = acc[2*h][reg]*acc[2*h][reg] + acc[2*h+1][reg]*acc[2*h+1][reg];
                    ss += __shfl_xor(ss, 1); ss += __shfl_xor(ss, 2);
                    ss += __shfl_xor(ss, 4); ss += __shfl_xor(ss, 8);
                    float f = sc / fmaxf(sqrtf(ss), 1e-12f);
                    acc[2*h][reg]   *= f;
                    acc[2*h+1][reg] *= f;
                }
            }
        }
        #pragma unroll
        for (int ct = 0; ct < 12; ct++) {
            int c = 16*ct + lr;
            #pragma unroll
            for (int reg = 0; reg < 4; reg++) {
                int row = m0 + 16*wave + 4*lg + reg;
                D[(size_t)row*DIMC + c] = (__bf16)acc[ct][reg];
            }
        }
    }
}

// ---------------- proj GEMM v4: bf16 A direct, bf16 W double-buffered, f32 out + bias ----------------
__global__ __launch_bounds__(256) void gemm_proj(
    const __bf16* __restrict__ A, const __bf16* __restrict__ W,
    const float* __restrict__ bias, float* __restrict__ D)
{
    __shared__ __bf16 Ws[2][192*40];
    int m0 = blockIdx.x * 64;
    int t  = threadIdx.x;
    int wave = t >> 6, lane = t & 63, lr = lane & 15, lg = lane >> 4;
    int r = m0 + 16*wave + lr;

    bf16x8 afr[6];
    #pragma unroll
    for (int ks = 0; ks < 6; ks++)
        afr[ks] = *(const bf16x8*)(A + (size_t)r*DIMC + 32*ks + 8*lg);

    f32x4 acc[12];
    #pragma unroll
    for (int i = 0; i < 12; i++) acc[i] = (f32x4){0.f,0.f,0.f,0.f};

    #pragma unroll
    for (int i = 0; i < 3; i++) {
        int c = t + 256*i;
        int row = c >> 2, cg = c & 3;
        uint4 v = *(const uint4*)(W + (size_t)row*DIMC + 8*cg);
        *(uint4*)&Ws[0][row*40 + 8*cg] = v;
    }

    #pragma unroll 1
    for (int ks = 0; ks < 6; ks++) {
        __syncthreads();
        if (ks < 5) {
            #pragma unroll
            for (int i = 0; i < 3; i++) {
                int c = t + 256*i;
                int row = c >> 2, cg = c & 3;
                uint4 v = *(const uint4*)(W + (size_t)row*DIMC + 32*(ks+1) + 8*cg);
                *(uint4*)&Ws[(ks+1)&1][row*40 + 8*cg] = v;
            }
        }
        const __bf16* Wb = Ws[ks&1];
        #pragma unroll
        for (int ct = 0; ct < 12; ct++) {
            bf16x8 bfrag = *(const bf16x8*)&Wb[(16*ct + lr)*40 + 8*lg];
            acc[ct] = mfma16(afr[ks], bfrag, acc[ct]);
        }
    }
    #pragma unroll
    for (int ct = 0; ct < 12; ct++) {
        int c = 16*ct + lr;
        float bv = bias[c];
        #pragma unroll
        for (int reg = 0; reg < 4; reg++) {
            int row = m0 + 16*wave + 4*lg + reg;
            D[(size_t)row*DIMC + c] = acc[ct][reg] + bv;
        }
    }
}

// ---------------- fused attention: 32x32 MFMA, K staged in LDS, rolled ks ----------------
// QK: S = mfma32(K, Q): lane holds col q=lane&31, rows m_off=(reg&3)+8*(reg>>2)+4*hi
// V^T LDS: linear pitch 360 ushorts (180 dwords == 20 mod 32 -> uniform 2/bank)
// K LDS: [m][36] bf16 (18 dwords, gcd(18,32)=2 -> 2-way max on write & b128 read)
// XCD swizzle: bh = (bid&7)*384 + (bid>>3)
#define VT_PITCH 360
#define K_PITCH  36
__global__ __launch_bounds__(256, 4) void attn_kernel(
    const __bf16* __restrict__ qb, const __bf16* __restrict__ kb, const __bf16* __restrict__ vb,
    const float* __restrict__ R, const unsigned* __restrict__ mbits,
    __bf16* __restrict__ cross)
{
    __shared__ __bf16 VTs[32*VT_PITCH];    // 23040 B
    __shared__ __bf16 Ks[NN*K_PITCH];      // 24696 B  (rows 0..342)

    int bid = blockIdx.x;
    int bh  = (bid & 7) * (BB*HH/8) + (bid >> 3);
    int b  = bh / HH;
    int h  = bh - b*HH;
    int w  = b & 63;
    int t  = threadIdx.x;

    const __bf16* Kb = kb + ((size_t)b*NN)*DIMC + 32*h;
    const __bf16* Vb = vb + ((size_t)b*NN)*DIMC + 32*h;
    const __bf16* Qb = qb + ((size_t)b*NN)*DIMC + 32*h;

    // stage V^T and K (consecutive threads -> consecutive chunks)
    for (int idx = t; idx < NN*4; idx += 256) {
        int part = idx / NN;
        int m    = idx - part*NN;
        union { uint4 u; __bf16 e[8]; } vv;
        vv.u = *(const uint4*)(Vb + (size_t)m*DIMC + 8*part);
        #pragma unroll
        for (int j = 0; j < 8; j++) VTs[(8*part + j)*VT_PITCH + m] = vv.e[j];
    }
    for (int idx = t; idx < NN*4; idx += 256) {
        int m = idx >> 2, part = idx & 3;
        uint4 kv = *(const uint4*)(Kb + (size_t)m*DIMC + 8*part);
        *(uint4*)&Ks[m*K_PITCH + 8*part] = kv;
    }
    for (int idx = t; idx < 32*9; idx += 256) {
        int d = idx / 9, m = NN + (idx - d*9);
        VTs[d*VT_PITCH + m] = (__bf16)0.f;
    }
    __syncthreads();

    int wave = t >> 6, lane = t & 63;
    int l31 = lane & 31, hi = lane >> 5;
    const f32x16 zero16 = {0.f,0.f,0.f,0.f,0.f,0.f,0.f,0.f,0.f,0.f,0.f,0.f,0.f,0.f,0.f,0.f};
    const __bf16* VTl = VTs + (size_t)l31*VT_PITCH;   // per-lane V row base

    for (int p = wave; p < 11; p += 4) {
        int q0 = 32*p;
        int rq = min(q0 + l31, NN-1);
        bf16x8 qf0 = *(const bf16x8*)(Qb + (size_t)rq*DIMC + 8*hi);        // kd 0..15
        bf16x8 qf1 = *(const bf16x8*)(Qb + (size_t)rq*DIMC + 16 + 8*hi);   // kd 16..31
        const float* Rrow = R + ((size_t)h*NN + rq)*352 + 4*hi;
        const unsigned* mp = mbits + ((size_t)(w*NN + rq))*16 + hi*8;
        uint4 mw = *(const uint4*)mp;
        uint2 mx = *(const uint2*)(mp + 4);
        unsigned long long ma = mw.x | ((unsigned long long)mw.y << 32);
        unsigned long long mbq = mw.z | ((unsigned long long)mw.w << 32);
        unsigned long long mc = mx.x | ((unsigned long long)mx.y << 32);

        f32x16 O = zero16;
        float dsum = 0.f;

        // prefetch K rows (from LDS) for ks=0
        bf16x8 kf0 = *(const bf16x8*)&Ks[l31*K_PITCH + 8*hi];
        bf16x8 kf1 = *(const bf16x8*)&Ks[l31*K_PITCH + 16 + 8*hi];

        for (int ks = 0; ks < 11; ks++) {
            // this-iter R loads (consumed after QK MFMAs)
            f32x4 rA = *(const f32x4*)(Rrow + 32*ks);
            f32x4 rB = *(const f32x4*)(Rrow + 32*ks + 8);
            f32x4 rC = *(const f32x4*)(Rrow + 32*ks + 16);
            f32x4 rD = *(const f32x4*)(Rrow + 32*ks + 24);
            // prefetch K (LDS) for ks+1
            bf16x8 kf0n = kf0, kf1n = kf1;
            if (ks < 10) {
                int krn = min(32*(ks+1) + l31, NN-1);
                kf0n = *(const bf16x8*)&Ks[krn*K_PITCH + 8*hi];
                kf1n = *(const bf16x8*)&Ks[krn*K_PITCH + 16 + 8*hi];
            }

            f32x16 s = mfma32(kf0, qf0, zero16);
            s = mfma32(kf1, qf1, s);

            unsigned bits = (unsigned)(ma & 0xFFFFu);
            ma = (ma >> 16) | (mbq << 48); mbq = (mbq >> 16) | (mc << 48); mc >>= 16;

            float pv[16];
            #pragma unroll
            for (int r = 0; r < 4; r++) {
                pv[r]    = (bits & (1u << r))      ? __builtin_amdgcn_exp2f(s[r])    * rA[r] : 0.f;
                pv[4+r]  = (bits & (1u << (4+r)))  ? __builtin_amdgcn_exp2f(s[4+r])  * rB[r] : 0.f;
                pv[8+r]  = (bits & (1u << (8+r)))  ? __builtin_amdgcn_exp2f(s[8+r])  * rC[r] : 0.f;
                pv[12+r] = (bits & (1u << (12+r))) ? __builtin_amdgcn_exp2f(s[12+r]) * rD[r] : 0.f;
            }
            {
                float t0 = pv[0]+pv[1], t1 = pv[2]+pv[3], t2 = pv[4]+pv[5], t3 = pv[6]+pv[7];
                float t4 = pv[8]+pv[9], t5 = pv[10]+pv[11], t6 = pv[12]+pv[13], t7 = pv[14]+pv[15];
                dsum += ((t0+t1)+(t2+t3)) + ((t4+t5)+(t6+t7));
            }
            // pack + permlane redistribution (C layout -> A layout)
            unsigned w0 = pack2(pv[0],  pv[1]),  w1 = pack2(pv[2],  pv[3]);
            unsigned w2 = pack2(pv[4],  pv[5]),  w3 = pack2(pv[6],  pv[7]);
            unsigned w4 = pack2(pv[8],  pv[9]),  w5 = pack2(pv[10], pv[11]);
            unsigned w6 = pack2(pv[12], pv[13]), w7 = pack2(pv[14], pv[15]);
            pl32_swap(w0, w2); pl32_swap(w1, w3);
            pl32_swap(w4, w6); pl32_swap(w5, w7);
            union { unsigned u[4]; bf16x8 f; } fa, fb;
            fa.u[0] = w0; fa.u[1] = w1; fa.u[2] = w2; fa.u[3] = w3;   // m in [32ks, 32ks+16)
            fb.u[0] = w4; fb.u[1] = w5; fb.u[2] = w6; fb.u[3] = w7;   // m in [32ks+16, 32ks+32)

            bf16x8 v0 = *(const bf16x8*)&VTl[32*ks + 8*hi];
            bf16x8 v1 = *(const bf16x8*)&VTl[32*ks + 16 + 8*hi];
            O = mfma32(fa.f, v0, O);
            O = mfma32(fb.f, v1, O);

            kf0 = kf0n; kf1 = kf1n;
        }

        dsum += __shfl_xor(dsum, 32);
        float dinv = 1.f / dsum;

        #pragma unroll
        for (int r = 0; r < 16; r++) {
            int off = (r & 3) + 8*(r >> 2) + 4*hi;
            float dv = __shfl(dinv, off);
            int qr = q0 + off;
            if (qr < NN)
                cross[((size_t)b*NN + qr)*DIMC + 32*h + l31] = (__bf16)(O[r] * dv);
        }
    }
}

extern "C" void kernel_launch(void* const* d_in, const int* in_sizes, int n_in,
                              void* d_out, int out_size, void* d_ws, size_t ws_size,
                              hipStream_t stream) {
    const float* x           = (const float*)d_in[0];
    const float* y           = (const float*)d_in[1];
    const float* mask        = (const float*)d_in[2];
    const float* qkv1_w      = (const float*)d_in[3];
    const float* qkv2_w      = (const float*)d_in[4];
    const float* v1_bias     = (const float*)d_in[6];
    const float* q2_bias     = (const float*)d_in[7];
    const float* logit_scale = (const float*)d_in[9];
    const float* cpb_w1      = (const float*)d_in[10];
    const float* cpb_b1      = (const float*)d_in[11];
    const float* cpb_w2      = (const float*)d_in[12];
    const float* proj_w      = (const float*)d_in[13];
    const float* proj_b      = (const float*)d_in[14];
    const float* rel_table   = (const float*)d_in[15];
    const int*   rp_index    = (const int*)d_in[16];

    char* ws = (char*)d_ws;
    float*    table  = (float*)(ws + OFF_TABLE);
    float*    R      = (float*)(ws + OFF_R);
    unsigned* mb     = (unsigned*)(ws + OFF_MB);
    __bf16*   q_bf   = (__bf16*)(ws + OFF_QB);
    __bf16*   k_bf   = (__bf16*)(ws + OFF_KB);
    __bf16*   v_bf   = (__bf16*)(ws + OFF_VB);
    __bf16*   crossb = (__bf16*)(ws + OFF_CROSS);
    __bf16*   wbf    = (__bf16*)(ws + OFF_WB);

    __bf16* w_k    = wbf + 192*DIMC;        // qkv1 rows 192..383
    __bf16* w_v    = wbf + 384*DIMC;        // qkv1 rows 384..575
    __bf16* w_q    = wbf + 576*DIMC;        // qkv2 rows 0..191
    __bf16* w_proj = wbf + 1152*DIMC;

    cpb_table_kernel<<<2197, 256, 0, stream>>>(rel_table, cpb_w1, cpb_b1, cpb_w2, table);
    r_kernel<<<(HH*NN*352 + 255)/256, 256, 0, stream>>>(table, rp_index, R);
    mbits2_kernel<<<(64*NN*2 + 255)/256, 256, 0, stream>>>(mask, mb);
    wcvt_kernel<<<(258048/4 + 255)/256, 256, 0, stream>>>(qkv1_w, qkv2_w, proj_w, wbf);
    // x -> k (norm, no bias), v (+v1_bias, no norm)
    gemm_f32in<<<MM/64, 256, 0, stream>>>(x, logit_scale,
                                          w_k, nullptr, 1, k_bf,
                                          w_v, v1_bias, 0, v_bf);
    // y -> q (+q2_bias, norm+scale*log2e)
    gemm_f32in<<<MM/64, 256, 0, stream>>>(y, logit_scale,
                                          w_q, q2_bias, 2, q_bf,
                                          nullptr, nullptr, 0, nullptr);

    attn_kernel<<<BB*HH, 256, 0, stream>>>(q_bf, k_bf, v_bf, R, mb, crossb);

    gemm_proj<<<MM/64, 256, 0, stream>>>(crossb, w_proj, proj_b, (float*)d_out);
}

// Round 16
// 505.736 us; speedup vs baseline: 2.0950x; 2.0950x over previous
//
#include <hip/hip_runtime.h>

#define HH   6
#define NN   343
#define BB   512
#define DIMC 192
#define MM   (BB*NN)      // 175616

// workspace offsets (bytes)
#define OFF_TABLE 0                        // [2197][8] f32
#define OFF_R     70400                    // [6][343][352] f32  (exp(rpb-26), zero tail)
#define OFF_MB    2968064                  // [64*343][16] u32   (bit-packed mask, 32x32-reg order)
#define OFF_QB    4372992                  // [M][192] bf16 (normalized * scale * log2e)
#define OFF_KB    (OFF_QB + 67436544)      // [M][192] bf16 (normalized)
#define OFF_VB    (OFF_KB + 67436544)
#define OFF_CROSS (OFF_VB + 67436544)
#define OFF_WB    (OFF_CROSS + 67436544)   // [1344][192] bf16: qkv1(576), qkv2(576), proj(192)
// end = 274,635,264 bytes

typedef __bf16 bf16x8 __attribute__((ext_vector_type(8)));
typedef float  f32x4  __attribute__((ext_vector_type(4)));
typedef float  f32x16 __attribute__((ext_vector_type(16)));

__device__ __forceinline__ f32x4 mfma16(bf16x8 a, bf16x8 b, f32x4 c) {
    return __builtin_amdgcn_mfma_f32_16x16x32_bf16(a, b, c, 0, 0, 0);
}
__device__ __forceinline__ f32x16 mfma32(bf16x8 a, bf16x8 b, f32x16 c) {
    return __builtin_amdgcn_mfma_f32_32x32x16_bf16(a, b, c, 0, 0, 0);
}

__device__ __forceinline__ unsigned pack2(float a, float b) {
    union { __bf16 h[2]; unsigned u; } x;
    x.h[0] = (__bf16)a; x.h[1] = (__bf16)b;
    return x.u;
}
// swaps a[32:63] <-> b[0:31]
__device__ __forceinline__ void pl32_swap(unsigned &a, unsigned &b) {
    asm volatile("v_permlane32_swap_b32 %0, %1" : "+v"(a), "+v"(b));
}

// ---------------- K1: CPB MLP -> table[2197][8] ----------------
__global__ __launch_bounds__(256) void cpb_table_kernel(
    const float* __restrict__ rel_table, const float* __restrict__ w1,
    const float* __restrict__ b1, const float* __restrict__ w2,
    float* __restrict__ table)
{
    int i = blockIdx.x;
    int t = threadIdx.x;
    float t0 = rel_table[i*3+0], t1 = rel_table[i*3+1], t2 = rel_table[i*3+2];
    float acc[HH];
    #pragma unroll
    for (int h = 0; h < HH; h++) acc[h] = 0.f;
    for (int j = t; j < 512; j += 256) {
        float hv = w1[j*3+0]*t0 + w1[j*3+1]*t1 + w1[j*3+2]*t2 + b1[j];
        hv = fmaxf(hv, 0.f);
        #pragma unroll
        for (int h = 0; h < HH; h++) acc[h] += w2[h*512+j] * hv;
    }
    __shared__ float red[256*HH];
    #pragma unroll
    for (int h = 0; h < HH; h++) red[t*HH+h] = acc[h];
    __syncthreads();
    for (int s = 128; s > 0; s >>= 1) {
        if (t < s) {
            #pragma unroll
            for (int h = 0; h < HH; h++) red[t*HH+h] += red[(t+s)*HH+h];
        }
        __syncthreads();
    }
    if (t < HH) table[(size_t)i*8 + t] = red[t];
}

// ---------------- K2: R = exp(16*sigmoid(gather) - 26), [6][343][352] ----------------
__global__ __launch_bounds__(256) void r_kernel(
    const float* __restrict__ table, const int* __restrict__ rp_index,
    float* __restrict__ R)
{
    int id = blockIdx.x*256 + threadIdx.x;
    if (id >= HH*NN*352) return;
    int h   = id / (NN*352);
    int rem = id - h*(NN*352);
    int n   = rem / 352;
    int mc  = rem - n*352;
    float out = 0.f;
    if (mc < NN) {
        float v = table[(size_t)rp_index[n*NN+mc]*8 + h];
        float r = 16.f / (1.f + __expf(-v));
        out = __expf(r - 26.f);
    }
    R[id] = out;
}

// ---------------- K3: bit-pack mask for 32x32 reg order ----------------
__global__ __launch_bounds__(256) void mbits2_kernel(
    const float* __restrict__ mask, unsigned* __restrict__ mb)
{
    int id = blockIdx.x*256 + threadIdx.x;    // 64*343*2 threads
    if (id >= 64*NN*2) return;
    int hi  = id & 1;
    int row = id >> 1;                         // w*343 + n
    const float* mrow = mask + (size_t)row*NN;
    unsigned* out = mb + (size_t)row*16 + hi*8;
    #pragma unroll
    for (int wd = 0; wd < 6; wd++) {
        unsigned u = 0;
        #pragma unroll
        for (int p = 0; p < 32; p++) {
            int g = 32*wd + p;
            int ks = g >> 4, r = g & 15;
            int m = 32*ks + (r&3) + 8*(r>>2) + 4*hi;
            if (m < NN && mrow[m] > -50.f) u |= (1u << p);
        }
        out[wd] = u;
    }
    out[6] = 0u; out[7] = 0u;
}

// ---------------- K4: convert weights f32 -> bf16 (qkv1 | qkv2 | proj) ----------------
__global__ __launch_bounds__(256) void wcvt_kernel(
    const float* __restrict__ qkv1, const float* __restrict__ qkv2,
    const float* __restrict__ proj, __bf16* __restrict__ out)
{
    int i = blockIdx.x*256 + threadIdx.x;   // float4 index
    const int n1 = 110592/4, n2 = 221184/4, n3 = 258048/4;
    if (i >= n3) return;
    const float* src; int off;
    if (i < n1)      { src = qkv1; off = i; }
    else if (i < n2) { src = qkv2; off = i - n1; }
    else             { src = proj; off = i - n2; }
    float4 v = ((const float4*)src)[off];
    __bf16* d = out + (size_t)i*4;
    d[0] = (__bf16)v.x; d[1] = (__bf16)v.y; d[2] = (__bf16)v.z; d[3] = (__bf16)v.w;
}

// ---------------- GEMM v3: f32 A direct-from-global, bf16 W staged in LDS, 2 phases ----------------
// norm: 0 = none, 1 = k-norm (1/|k|), 2 = q-norm (scale*log2e/|q|)
__global__ __launch_bounds__(256) void gemm_f32in(
    const float* __restrict__ A, const float* __restrict__ ls,
    const __bf16* __restrict__ W0, const float* __restrict__ bias0, int norm0, __bf16* __restrict__ D0,
    const __bf16* __restrict__ W1, const float* __restrict__ bias1, int norm1, __bf16* __restrict__ D1)
{
    __shared__ __bf16 Ws[192*40];
    int m0 = blockIdx.x * 64;
    int t  = threadIdx.x;
    int wave = t >> 6, lane = t & 63, lr = lane & 15, lg = lane >> 4;
    int r = m0 + 16*wave + lr;

    // A row fragments, f32 -> bf16, kept in regs across phases
    bf16x8 afr[6];
    #pragma unroll
    for (int ks = 0; ks < 6; ks++) {
        const float* ap = A + (size_t)r*DIMC + 32*ks + 8*lg;
        float4 v0 = *(const float4*)ap;
        float4 v1 = *(const float4*)(ap + 4);
        bf16x8 f;
        f[0]=(__bf16)v0.x; f[1]=(__bf16)v0.y; f[2]=(__bf16)v0.z; f[3]=(__bf16)v0.w;
        f[4]=(__bf16)v1.x; f[5]=(__bf16)v1.y; f[6]=(__bf16)v1.z; f[7]=(__bf16)v1.w;
        afr[ks] = f;
    }

    #pragma unroll 1
    for (int phase = 0; phase < 2; phase++) {
        const __bf16* W    = phase ? W1 : W0;
        if (!W) break;
        const float* bias  = phase ? bias1 : bias0;
        int          nrm   = phase ? norm1 : norm0;
        __bf16*      D     = phase ? D1 : D0;
        f32x4 acc[12];
        #pragma unroll
        for (int i = 0; i < 12; i++) acc[i] = (f32x4){0.f,0.f,0.f,0.f};
        for (int ks = 0; ks < 6; ks++) {
            __syncthreads();
            #pragma unroll
            for (int i = 0; i < 3; i++) {
                int c = t + 256*i;         // 768 uint4 chunks = 192 rows x 4 col-groups
                int row = c >> 2, cg = c & 3;
                uint4 v = *(const uint4*)(W + (size_t)row*DIMC + 32*ks + 8*cg);
                *(uint4*)&Ws[row*40 + 8*cg] = v;
            }
            __syncthreads();
            #pragma unroll
            for (int ct = 0; ct < 12; ct++) {
                bf16x8 bfrag = *(const bf16x8*)&Ws[(16*ct + lr)*40 + 8*lg];
                acc[ct] = mfma16(afr[ks], bfrag, acc[ct]);
            }
        }
        if (bias) {
            #pragma unroll
            for (int ct = 0; ct < 12; ct++) {
                float bv = bias[16*ct + lr];
                #pragma unroll
                for (int reg = 0; reg < 4; reg++) acc[ct][reg] += bv;
            }
        }
        if (nrm) {
            #pragma unroll
            for (int h = 0; h < HH; h++) {
                float sc = 1.f;
                if (nrm == 2) sc = __expf(fminf(ls[h], 4.6051702f)) * 1.4426950408889634f;
                #pragma unroll
                for (int reg = 0; reg < 4; reg++) {
                    float ss = acc[2*h][reg]*acc[2*h][reg] + acc[2*h+1][reg]*acc[2*h+1][reg];
                    ss += __shfl_xor(ss, 1); ss += __shfl_xor(ss, 2);
                    ss += __shfl_xor(ss, 4); ss += __shfl_xor(ss, 8);
                    float f = sc / fmaxf(sqrtf(ss), 1e-12f);
                    acc[2*h][reg]   *= f;
                    acc[2*h+1][reg] *= f;
                }
            }
        }
        #pragma unroll
        for (int ct = 0; ct < 12; ct++) {
            int c = 16*ct + lr;
            #pragma unroll
            for (int reg = 0; reg < 4; reg++) {
                int row = m0 + 16*wave + 4*lg + reg;
                D[(size_t)row*DIMC + c] = (__bf16)acc[ct][reg];
            }
        }
    }
}

// ---------------- proj GEMM v3: bf16 A direct, bf16 W staged in LDS, f32 out + bias ----------------
__global__ __launch_bounds__(256) void gemm_proj(
    const __bf16* __restrict__ A, const __bf16* __restrict__ W,
    const float* __restrict__ bias, float* __restrict__ D)
{
    __shared__ __bf16 Ws[192*40];
    int m0 = blockIdx.x * 64;
    int t  = threadIdx.x;
    int wave = t >> 6, lane = t & 63, lr = lane & 15, lg = lane >> 4;
    int r = m0 + 16*wave + lr;

    bf16x8 afr[6];
    #pragma unroll
    for (int ks = 0; ks < 6; ks++)
        afr[ks] = *(const bf16x8*)(A + (size_t)r*DIMC + 32*ks + 8*lg);

    f32x4 acc[12];
    #pragma unroll
    for (int i = 0; i < 12; i++) acc[i] = (f32x4){0.f,0.f,0.f,0.f};
    for (int ks = 0; ks < 6; ks++) {
        __syncthreads();
        #pragma unroll
        for (int i = 0; i < 3; i++) {
            int c = t + 256*i;
            int row = c >> 2, cg = c & 3;
            uint4 v = *(const uint4*)(W + (size_t)row*DIMC + 32*ks + 8*cg);
            *(uint4*)&Ws[row*40 + 8*cg] = v;
        }
        __syncthreads();
        #pragma unroll
        for (int ct = 0; ct < 12; ct++) {
            bf16x8 bfrag = *(const bf16x8*)&Ws[(16*ct + lr)*40 + 8*lg];
            acc[ct] = mfma16(afr[ks], bfrag, acc[ct]);
        }
    }
    #pragma unroll
    for (int ct = 0; ct < 12; ct++) {
        int c = 16*ct + lr;
        float bv = bias[c];
        #pragma unroll
        for (int reg = 0; reg < 4; reg++) {
            int row = m0 + 16*wave + 4*lg + reg;
            D[(size_t)row*DIMC + c] = acc[ct][reg] + bv;
        }
    }
}

// ---------------- fused attention: 32x32 MFMA, K staged in LDS, rolled ks ----------------
// QK: S = mfma32(K, Q): lane holds col q=lane&31, rows m_off=(reg&3)+8*(reg>>2)+4*hi
// V^T LDS: linear pitch 360 ushorts (180 dwords == 20 mod 32 -> uniform 2/bank)
// K LDS: [m][36] bf16 (18 dwords, gcd(18,32)=2 -> 2-way max on write & b128 read)
// XCD swizzle: bh = (bid&7)*384 + (bid>>3); s_setprio(1) around MFMA pairs (T5)
#define VT_PITCH 360
#define K_PITCH  36
__global__ __launch_bounds__(256, 4) void attn_kernel(
    const __bf16* __restrict__ qb, const __bf16* __restrict__ kb, const __bf16* __restrict__ vb,
    const float* __restrict__ R, const unsigned* __restrict__ mbits,
    __bf16* __restrict__ cross)
{
    __shared__ __bf16 VTs[32*VT_PITCH];    // 23040 B
    __shared__ __bf16 Ks[NN*K_PITCH];      // 24696 B  (rows 0..342)

    int bid = blockIdx.x;
    int bh  = (bid & 7) * (BB*HH/8) + (bid >> 3);
    int b  = bh / HH;
    int h  = bh - b*HH;
    int w  = b & 63;
    int t  = threadIdx.x;

    const __bf16* Kb = kb + ((size_t)b*NN)*DIMC + 32*h;
    const __bf16* Vb = vb + ((size_t)b*NN)*DIMC + 32*h;
    const __bf16* Qb = qb + ((size_t)b*NN)*DIMC + 32*h;

    // stage V^T and K (consecutive threads -> consecutive chunks)
    for (int idx = t; idx < NN*4; idx += 256) {
        int part = idx / NN;
        int m    = idx - part*NN;
        union { uint4 u; __bf16 e[8]; } vv;
        vv.u = *(const uint4*)(Vb + (size_t)m*DIMC + 8*part);
        #pragma unroll
        for (int j = 0; j < 8; j++) VTs[(8*part + j)*VT_PITCH + m] = vv.e[j];
    }
    for (int idx = t; idx < NN*4; idx += 256) {
        int m = idx >> 2, part = idx & 3;
        uint4 kv = *(const uint4*)(Kb + (size_t)m*DIMC + 8*part);
        *(uint4*)&Ks[m*K_PITCH + 8*part] = kv;
    }
    for (int idx = t; idx < 32*9; idx += 256) {
        int d = idx / 9, m = NN + (idx - d*9);
        VTs[d*VT_PITCH + m] = (__bf16)0.f;
    }
    __syncthreads();

    int wave = t >> 6, lane = t & 63;
    int l31 = lane & 31, hi = lane >> 5;
    const f32x16 zero16 = {0.f,0.f,0.f,0.f,0.f,0.f,0.f,0.f,0.f,0.f,0.f,0.f,0.f,0.f,0.f,0.f};
    const __bf16* VTl = VTs + (size_t)l31*VT_PITCH;   // per-lane V row base

    for (int p = wave; p < 11; p += 4) {
        int q0 = 32*p;
        int rq = min(q0 + l31, NN-1);
        bf16x8 qf0 = *(const bf16x8*)(Qb + (size_t)rq*DIMC + 8*hi);        // kd 0..15
        bf16x8 qf1 = *(const bf16x8*)(Qb + (size_t)rq*DIMC + 16 + 8*hi);   // kd 16..31
        const float* Rrow = R + ((size_t)h*NN + rq)*352 + 4*hi;
        const unsigned* mp = mbits + ((size_t)(w*NN + rq))*16 + hi*8;
        uint4 mw = *(const uint4*)mp;
        uint2 mx = *(const uint2*)(mp + 4);
        unsigned long long ma = mw.x | ((unsigned long long)mw.y << 32);
        unsigned long long mbq = mw.z | ((unsigned long long)mw.w << 32);
        unsigned long long mc = mx.x | ((unsigned long long)mx.y << 32);

        f32x16 O = zero16;
        float dsum = 0.f;

        // prefetch K rows (from LDS) for ks=0
        bf16x8 kf0 = *(const bf16x8*)&Ks[l31*K_PITCH + 8*hi];
        bf16x8 kf1 = *(const bf16x8*)&Ks[l31*K_PITCH + 16 + 8*hi];

        for (int ks = 0; ks < 11; ks++) {
            // this-iter R loads (consumed after QK MFMAs)
            f32x4 rA = *(const f32x4*)(Rrow + 32*ks);
            f32x4 rB = *(const f32x4*)(Rrow + 32*ks + 8);
            f32x4 rC = *(const f32x4*)(Rrow + 32*ks + 16);
            f32x4 rD = *(const f32x4*)(Rrow + 32*ks + 24);
            // prefetch K (LDS) for ks+1
            bf16x8 kf0n = kf0, kf1n = kf1;
            if (ks < 10) {
                int krn = min(32*(ks+1) + l31, NN-1);
                kf0n = *(const bf16x8*)&Ks[krn*K_PITCH + 8*hi];
                kf1n = *(const bf16x8*)&Ks[krn*K_PITCH + 16 + 8*hi];
            }

            __builtin_amdgcn_s_setprio(1);
            f32x16 s = mfma32(kf0, qf0, zero16);
            s = mfma32(kf1, qf1, s);
            __builtin_amdgcn_s_setprio(0);

            unsigned bits = (unsigned)(ma & 0xFFFFu);
            ma = (ma >> 16) | (mbq << 48); mbq = (mbq >> 16) | (mc << 48); mc >>= 16;

            float pv[16];
            #pragma unroll
            for (int r = 0; r < 4; r++) {
                pv[r]    = (bits & (1u << r))      ? __builtin_amdgcn_exp2f(s[r])    * rA[r] : 0.f;
                pv[4+r]  = (bits & (1u << (4+r)))  ? __builtin_amdgcn_exp2f(s[4+r])  * rB[r] : 0.f;
                pv[8+r]  = (bits & (1u << (8+r)))  ? __builtin_amdgcn_exp2f(s[8+r])  * rC[r] : 0.f;
                pv[12+r] = (bits & (1u << (12+r))) ? __builtin_amdgcn_exp2f(s[12+r]) * rD[r] : 0.f;
            }
            {
                float t0 = pv[0]+pv[1], t1 = pv[2]+pv[3], t2 = pv[4]+pv[5], t3 = pv[6]+pv[7];
                float t4 = pv[8]+pv[9], t5 = pv[10]+pv[11], t6 = pv[12]+pv[13], t7 = pv[14]+pv[15];
                dsum += ((t0+t1)+(t2+t3)) + ((t4+t5)+(t6+t7));
            }
            // pack + permlane redistribution (C layout -> A layout)
            unsigned w0 = pack2(pv[0],  pv[1]),  w1 = pack2(pv[2],  pv[3]);
            unsigned w2 = pack2(pv[4],  pv[5]),  w3 = pack2(pv[6],  pv[7]);
            unsigned w4 = pack2(pv[8],  pv[9]),  w5 = pack2(pv[10], pv[11]);
            unsigned w6 = pack2(pv[12], pv[13]), w7 = pack2(pv[14], pv[15]);
            pl32_swap(w0, w2); pl32_swap(w1, w3);
            pl32_swap(w4, w6); pl32_swap(w5, w7);
            union { unsigned u[4]; bf16x8 f; } fa, fb;
            fa.u[0] = w0; fa.u[1] = w1; fa.u[2] = w2; fa.u[3] = w3;   // m in [32ks, 32ks+16)
            fb.u[0] = w4; fb.u[1] = w5; fb.u[2] = w6; fb.u[3] = w7;   // m in [32ks+16, 32ks+32)

            bf16x8 v0 = *(const bf16x8*)&VTl[32*ks + 8*hi];
            bf16x8 v1 = *(const bf16x8*)&VTl[32*ks + 16 + 8*hi];
            __builtin_amdgcn_s_setprio(1);
            O = mfma32(fa.f, v0, O);
            O = mfma32(fb.f, v1, O);
            __builtin_amdgcn_s_setprio(0);

            kf0 = kf0n; kf1 = kf1n;
        }

        dsum += __shfl_xor(dsum, 32);
        float dinv = 1.f / dsum;

        #pragma unroll
        for (int r = 0; r < 16; r++) {
            int off = (r & 3) + 8*(r >> 2) + 4*hi;
            float dv = __shfl(dinv, off);
            int qr = q0 + off;
            if (qr < NN)
                cross[((size_t)b*NN + qr)*DIMC + 32*h + l31] = (__bf16)(O[r] * dv);
        }
    }
}

extern "C" void kernel_launch(void* const* d_in, const int* in_sizes, int n_in,
                              void* d_out, int out_size, void* d_ws, size_t ws_size,
                              hipStream_t stream) {
    const float* x           = (const float*)d_in[0];
    const float* y           = (const float*)d_in[1];
    const float* mask        = (const float*)d_in[2];
    const float* qkv1_w      = (const float*)d_in[3];
    const float* qkv2_w      = (const float*)d_in[4];
    const float* v1_bias     = (const float*)d_in[6];
    const float* q2_bias     = (const float*)d_in[7];
    const float* logit_scale = (const float*)d_in[9];
    const float* cpb_w1      = (const float*)d_in[10];
    const float* cpb_b1      = (const float*)d_in[11];
    const float* cpb_w2      = (const float*)d_in[12];
    const float* proj_w      = (const float*)d_in[13];
    const float* proj_b      = (const float*)d_in[14];
    const float* rel_table   = (const float*)d_in[15];
    const int*   rp_index    = (const int*)d_in[16];

    char* ws = (char*)d_ws;
    float*    table  = (float*)(ws + OFF_TABLE);
    float*    R      = (float*)(ws + OFF_R);
    unsigned* mb     = (unsigned*)(ws + OFF_MB);
    __bf16*   q_bf   = (__bf16*)(ws + OFF_QB);
    __bf16*   k_bf   = (__bf16*)(ws + OFF_KB);
    __bf16*   v_bf   = (__bf16*)(ws + OFF_VB);
    __bf16*   crossb = (__bf16*)(ws + OFF_CROSS);
    __bf16*   wbf    = (__bf16*)(ws + OFF_WB);

    __bf16* w_k    = wbf + 192*DIMC;        // qkv1 rows 192..383
    __bf16* w_v    = wbf + 384*DIMC;        // qkv1 rows 384..575
    __bf16* w_q    = wbf + 576*DIMC;        // qkv2 rows 0..191
    __bf16* w_proj = wbf + 1152*DIMC;

    cpb_table_kernel<<<2197, 256, 0, stream>>>(rel_table, cpb_w1, cpb_b1, cpb_w2, table);
    r_kernel<<<(HH*NN*352 + 255)/256, 256, 0, stream>>>(table, rp_index, R);
    mbits2_kernel<<<(64*NN*2 + 255)/256, 256, 0, stream>>>(mask, mb);
    wcvt_kernel<<<(258048/4 + 255)/256, 256, 0, stream>>>(qkv1_w, qkv2_w, proj_w, wbf);
    // x -> k (norm, no bias), v (+v1_bias, no norm)
    gemm_f32in<<<MM/64, 256, 0, stream>>>(x, logit_scale,
                                          w_k, nullptr, 1, k_bf,
                                          w_v, v1_bias, 0, v_bf);
    // y -> q (+q2_bias, norm+scale*log2e)
    gemm_f32in<<<MM/64, 256, 0, stream>>>(y, logit_scale,
                                          w_q, q2_bias, 2, q_bf,
                                          nullptr, nullptr, 0, nullptr);

    attn_kernel<<<BB*HH, 256, 0, stream>>>(q_bf, k_bf, v_bf, R, mb, crossb);

    gemm_proj<<<MM/64, 256, 0, stream>>>(crossb, w_proj, proj_b, (float*)d_out);
}

// Round 17
// 500.935 us; speedup vs baseline: 2.1151x; 1.0096x over previous
//
#include <hip/hip_runtime.h>

#define HH   6
#define NN   343
#define BB   512
#define DIMC 192
#define MM   (BB*NN)      // 175616

// workspace offsets (bytes)
#define OFF_TABLE 0                        // [2197][8] f32
#define OFF_R     70400                    // [6][343][352] f32  (exp(rpb-26), zero tail)
#define OFF_MB    2968064                  // [64*343][16] u32   (bit-packed mask, 32x32-reg order)
#define OFF_QB    4372992                  // [M][192] bf16 (normalized * scale * log2e)
#define OFF_KB    (OFF_QB + 67436544)      // [M][192] bf16 (normalized)
#define OFF_VB    (OFF_KB + 67436544)
#define OFF_CROSS (OFF_VB + 67436544)
#define OFF_WB    (OFF_CROSS + 67436544)   // [1344][192] bf16: qkv1(576), qkv2(576), proj(192)
// end = 274,635,264 bytes

typedef __bf16 bf16x8 __attribute__((ext_vector_type(8)));
typedef float  f32x4  __attribute__((ext_vector_type(4)));
typedef float  f32x16 __attribute__((ext_vector_type(16)));

__device__ __forceinline__ f32x4 mfma16(bf16x8 a, bf16x8 b, f32x4 c) {
    return __builtin_amdgcn_mfma_f32_16x16x32_bf16(a, b, c, 0, 0, 0);
}
__device__ __forceinline__ f32x16 mfma32(bf16x8 a, bf16x8 b, f32x16 c) {
    return __builtin_amdgcn_mfma_f32_32x32x16_bf16(a, b, c, 0, 0, 0);
}

__device__ __forceinline__ unsigned pack2(float a, float b) {
    union { __bf16 h[2]; unsigned u; } x;
    x.h[0] = (__bf16)a; x.h[1] = (__bf16)b;
    return x.u;
}
// swaps a[32:63] <-> b[0:31]
__device__ __forceinline__ void pl32_swap(unsigned &a, unsigned &b) {
    asm volatile("v_permlane32_swap_b32 %0, %1" : "+v"(a), "+v"(b));
}

// ---------------- K1: CPB MLP -> table[2197][8] ----------------
__global__ __launch_bounds__(256) void cpb_table_kernel(
    const float* __restrict__ rel_table, const float* __restrict__ w1,
    const float* __restrict__ b1, const float* __restrict__ w2,
    float* __restrict__ table)
{
    int i = blockIdx.x;
    int t = threadIdx.x;
    float t0 = rel_table[i*3+0], t1 = rel_table[i*3+1], t2 = rel_table[i*3+2];
    float acc[HH];
    #pragma unroll
    for (int h = 0; h < HH; h++) acc[h] = 0.f;
    for (int j = t; j < 512; j += 256) {
        float hv = w1[j*3+0]*t0 + w1[j*3+1]*t1 + w1[j*3+2]*t2 + b1[j];
        hv = fmaxf(hv, 0.f);
        #pragma unroll
        for (int h = 0; h < HH; h++) acc[h] += w2[h*512+j] * hv;
    }
    __shared__ float red[256*HH];
    #pragma unroll
    for (int h = 0; h < HH; h++) red[t*HH+h] = acc[h];
    __syncthreads();
    for (int s = 128; s > 0; s >>= 1) {
        if (t < s) {
            #pragma unroll
            for (int h = 0; h < HH; h++) red[t*HH+h] += red[(t+s)*HH+h];
        }
        __syncthreads();
    }
    if (t < HH) table[(size_t)i*8 + t] = red[t];
}

// ---------------- K2: R = exp(16*sigmoid(gather) - 26), [6][343][352] ----------------
__global__ __launch_bounds__(256) void r_kernel(
    const float* __restrict__ table, const int* __restrict__ rp_index,
    float* __restrict__ R)
{
    int id = blockIdx.x*256 + threadIdx.x;
    if (id >= HH*NN*352) return;
    int h   = id / (NN*352);
    int rem = id - h*(NN*352);
    int n   = rem / 352;
    int mc  = rem - n*352;
    float out = 0.f;
    if (mc < NN) {
        float v = table[(size_t)rp_index[n*NN+mc]*8 + h];
        float r = 16.f / (1.f + __expf(-v));
        out = __expf(r - 26.f);
    }
    R[id] = out;
}

// ---------------- K3: bit-pack mask for 32x32 reg order ----------------
__global__ __launch_bounds__(256) void mbits2_kernel(
    const float* __restrict__ mask, unsigned* __restrict__ mb)
{
    int id = blockIdx.x*256 + threadIdx.x;    // 64*343*2 threads
    if (id >= 64*NN*2) return;
    int hi  = id & 1;
    int row = id >> 1;                         // w*343 + n
    const float* mrow = mask + (size_t)row*NN;
    unsigned* out = mb + (size_t)row*16 + hi*8;
    #pragma unroll
    for (int wd = 0; wd < 6; wd++) {
        unsigned u = 0;
        #pragma unroll
        for (int p = 0; p < 32; p++) {
            int g = 32*wd + p;
            int ks = g >> 4, r = g & 15;
            int m = 32*ks + (r&3) + 8*(r>>2) + 4*hi;
            if (m < NN && mrow[m] > -50.f) u |= (1u << p);
        }
        out[wd] = u;
    }
    out[6] = 0u; out[7] = 0u;
}

// ---------------- K4: convert weights f32 -> bf16 (qkv1 | qkv2 | proj) ----------------
__global__ __launch_bounds__(256) void wcvt_kernel(
    const float* __restrict__ qkv1, const float* __restrict__ qkv2,
    const float* __restrict__ proj, __bf16* __restrict__ out)
{
    int i = blockIdx.x*256 + threadIdx.x;   // float4 index
    const int n1 = 110592/4, n2 = 221184/4, n3 = 258048/4;
    if (i >= n3) return;
    const float* src; int off;
    if (i < n1)      { src = qkv1; off = i; }
    else if (i < n2) { src = qkv2; off = i - n1; }
    else             { src = proj; off = i - n2; }
    float4 v = ((const float4*)src)[off];
    __bf16* d = out + (size_t)i*4;
    d[0] = (__bf16)v.x; d[1] = (__bf16)v.y; d[2] = (__bf16)v.z; d[3] = (__bf16)v.w;
}

// ---------------- GEMM v3: f32 A direct-from-global, bf16 W staged in LDS, 2 phases ----------------
// norm: 0 = none, 1 = k-norm (1/|k|), 2 = q-norm (scale*log2e/|q|)
__global__ __launch_bounds__(256) void gemm_f32in(
    const float* __restrict__ A, const float* __restrict__ ls,
    const __bf16* __restrict__ W0, const float* __restrict__ bias0, int norm0, __bf16* __restrict__ D0,
    const __bf16* __restrict__ W1, const float* __restrict__ bias1, int norm1, __bf16* __restrict__ D1)
{
    __shared__ __bf16 Ws[192*40];
    int m0 = blockIdx.x * 64;
    int t  = threadIdx.x;
    int wave = t >> 6, lane = t & 63, lr = lane & 15, lg = lane >> 4;
    int r = m0 + 16*wave + lr;

    // A row fragments, f32 -> bf16, kept in regs across phases
    bf16x8 afr[6];
    #pragma unroll
    for (int ks = 0; ks < 6; ks++) {
        const float* ap = A + (size_t)r*DIMC + 32*ks + 8*lg;
        float4 v0 = *(const float4*)ap;
        float4 v1 = *(const float4*)(ap + 4);
        bf16x8 f;
        f[0]=(__bf16)v0.x; f[1]=(__bf16)v0.y; f[2]=(__bf16)v0.z; f[3]=(__bf16)v0.w;
        f[4]=(__bf16)v1.x; f[5]=(__bf16)v1.y; f[6]=(__bf16)v1.z; f[7]=(__bf16)v1.w;
        afr[ks] = f;
    }

    #pragma unroll 1
    for (int phase = 0; phase < 2; phase++) {
        const __bf16* W    = phase ? W1 : W0;
        if (!W) break;
        const float* bias  = phase ? bias1 : bias0;
        int          nrm   = phase ? norm1 : norm0;
        __bf16*      D     = phase ? D1 : D0;
        f32x4 acc[12];
        #pragma unroll
        for (int i = 0; i < 12; i++) acc[i] = (f32x4){0.f,0.f,0.f,0.f};
        for (int ks = 0; ks < 6; ks++) {
            __syncthreads();
            #pragma unroll
            for (int i = 0; i < 3; i++) {
                int c = t + 256*i;         // 768 uint4 chunks = 192 rows x 4 col-groups
                int row = c >> 2, cg = c & 3;
                uint4 v = *(const uint4*)(W + (size_t)row*DIMC + 32*ks + 8*cg);
                *(uint4*)&Ws[row*40 + 8*cg] = v;
            }
            __syncthreads();
            #pragma unroll
            for (int ct = 0; ct < 12; ct++) {
                bf16x8 bfrag = *(const bf16x8*)&Ws[(16*ct + lr)*40 + 8*lg];
                acc[ct] = mfma16(afr[ks], bfrag, acc[ct]);
            }
        }
        if (bias) {
            #pragma unroll
            for (int ct = 0; ct < 12; ct++) {
                float bv = bias[16*ct + lr];
                #pragma unroll
                for (int reg = 0; reg < 4; reg++) acc[ct][reg] += bv;
            }
        }
        if (nrm) {
            #pragma unroll
            for (int h = 0; h < HH; h++) {
                float sc = 1.f;
                if (nrm == 2) sc = __expf(fminf(ls[h], 4.6051702f)) * 1.4426950408889634f;
                #pragma unroll
                for (int reg = 0; reg < 4; reg++) {
                    float ss = acc[2*h][reg]*acc[2*h][reg] + acc[2*h+1][reg]*acc[2*h+1][reg];
                    ss += __shfl_xor(ss, 1); ss += __shfl_xor(ss, 2);
                    ss += __shfl_xor(ss, 4); ss += __shfl_xor(ss, 8);
                    float f = sc / fmaxf(sqrtf(ss), 1e-12f);
                    acc[2*h][reg]   *= f;
                    acc[2*h+1][reg] *= f;
                }
            }
        }
        #pragma unroll
        for (int ct = 0; ct < 12; ct++) {
            int c = 16*ct + lr;
            #pragma unroll
            for (int reg = 0; reg < 4; reg++) {
                int row = m0 + 16*wave + 4*lg + reg;
                D[(size_t)row*DIMC + c] = (__bf16)acc[ct][reg];
            }
        }
    }
}

// ---------------- proj GEMM v3: bf16 A direct, bf16 W staged in LDS, f32 out + bias ----------------
__global__ __launch_bounds__(256) void gemm_proj(
    const __bf16* __restrict__ A, const __bf16* __restrict__ W,
    const float* __restrict__ bias, float* __restrict__ D)
{
    __shared__ __bf16 Ws[192*40];
    int m0 = blockIdx.x * 64;
    int t  = threadIdx.x;
    int wave = t >> 6, lane = t & 63, lr = lane & 15, lg = lane >> 4;
    int r = m0 + 16*wave + lr;

    bf16x8 afr[6];
    #pragma unroll
    for (int ks = 0; ks < 6; ks++)
        afr[ks] = *(const bf16x8*)(A + (size_t)r*DIMC + 32*ks + 8*lg);

    f32x4 acc[12];
    #pragma unroll
    for (int i = 0; i < 12; i++) acc[i] = (f32x4){0.f,0.f,0.f,0.f};
    for (int ks = 0; ks < 6; ks++) {
        __syncthreads();
        #pragma unroll
        for (int i = 0; i < 3; i++) {
            int c = t + 256*i;
            int row = c >> 2, cg = c & 3;
            uint4 v = *(const uint4*)(W + (size_t)row*DIMC + 32*ks + 8*cg);
            *(uint4*)&Ws[row*40 + 8*cg] = v;
        }
        __syncthreads();
        #pragma unroll
        for (int ct = 0; ct < 12; ct++) {
            bf16x8 bfrag = *(const bf16x8*)&Ws[(16*ct + lr)*40 + 8*lg];
            acc[ct] = mfma16(afr[ks], bfrag, acc[ct]);
        }
    }
    #pragma unroll
    for (int ct = 0; ct < 12; ct++) {
        int c = 16*ct + lr;
        float bv = bias[c];
        #pragma unroll
        for (int reg = 0; reg < 4; reg++) {
            int row = m0 + 16*wave + 4*lg + reg;
            D[(size_t)row*DIMC + c] = acc[ct][reg] + bv;
        }
    }
}

// ---------------- fused attention: 32x32 MFMA, K staged in LDS, rolled ks ----------------
// QK: S = mfma32(K, Q): lane holds col q=lane&31, rows m_off=(reg&3)+8*(reg>>2)+4*hi
// V^T LDS: linear pitch 360 ushorts (180 dwords == 20 mod 32 -> uniform 2/bank)
// K LDS: [m][36] bf16 (18 dwords, gcd(18,32)=2 -> 2-way max on write & b128 read)
// XCD swizzle: bh = (bid&7)*384 + (bid>>3)
#define VT_PITCH 360
#define K_PITCH  36
__global__ __launch_bounds__(256, 4) void attn_kernel(
    const __bf16* __restrict__ qb, const __bf16* __restrict__ kb, const __bf16* __restrict__ vb,
    const float* __restrict__ R, const unsigned* __restrict__ mbits,
    __bf16* __restrict__ cross)
{
    __shared__ __bf16 VTs[32*VT_PITCH];    // 23040 B
    __shared__ __bf16 Ks[NN*K_PITCH];      // 24696 B  (rows 0..342)

    int bid = blockIdx.x;
    int bh  = (bid & 7) * (BB*HH/8) + (bid >> 3);
    int b  = bh / HH;
    int h  = bh - b*HH;
    int w  = b & 63;
    int t  = threadIdx.x;

    const __bf16* Kb = kb + ((size_t)b*NN)*DIMC + 32*h;
    const __bf16* Vb = vb + ((size_t)b*NN)*DIMC + 32*h;
    const __bf16* Qb = qb + ((size_t)b*NN)*DIMC + 32*h;

    // stage V^T and K (consecutive threads -> consecutive chunks)
    for (int idx = t; idx < NN*4; idx += 256) {
        int part = idx / NN;
        int m    = idx - part*NN;
        union { uint4 u; __bf16 e[8]; } vv;
        vv.u = *(const uint4*)(Vb + (size_t)m*DIMC + 8*part);
        #pragma unroll
        for (int j = 0; j < 8; j++) VTs[(8*part + j)*VT_PITCH + m] = vv.e[j];
    }
    for (int idx = t; idx < NN*4; idx += 256) {
        int m = idx >> 2, part = idx & 3;
        uint4 kv = *(const uint4*)(Kb + (size_t)m*DIMC + 8*part);
        *(uint4*)&Ks[m*K_PITCH + 8*part] = kv;
    }
    for (int idx = t; idx < 32*9; idx += 256) {
        int d = idx / 9, m = NN + (idx - d*9);
        VTs[d*VT_PITCH + m] = (__bf16)0.f;
    }
    __syncthreads();

    int wave = t >> 6, lane = t & 63;
    int l31 = lane & 31, hi = lane >> 5;
    const f32x16 zero16 = {0.f,0.f,0.f,0.f,0.f,0.f,0.f,0.f,0.f,0.f,0.f,0.f,0.f,0.f,0.f,0.f};
    const __bf16* VTl = VTs + (size_t)l31*VT_PITCH;   // per-lane V row base

    for (int p = wave; p < 11; p += 4) {
        int q0 = 32*p;
        int rq = min(q0 + l31, NN-1);
        bf16x8 qf0 = *(const bf16x8*)(Qb + (size_t)rq*DIMC + 8*hi);        // kd 0..15
        bf16x8 qf1 = *(const bf16x8*)(Qb + (size_t)rq*DIMC + 16 + 8*hi);   // kd 16..31
        const float* Rrow = R + ((size_t)h*NN + rq)*352 + 4*hi;
        const unsigned* mp = mbits + ((size_t)(w*NN + rq))*16 + hi*8;
        uint4 mw = *(const uint4*)mp;
        uint2 mx = *(const uint2*)(mp + 4);
        unsigned long long ma = mw.x | ((unsigned long long)mw.y << 32);
        unsigned long long mbq = mw.z | ((unsigned long long)mw.w << 32);
        unsigned long long mc = mx.x | ((unsigned long long)mx.y << 32);

        f32x16 O = zero16;
        float dsum = 0.f;

        // prefetch K rows (from LDS) for ks=0
        bf16x8 kf0 = *(const bf16x8*)&Ks[l31*K_PITCH + 8*hi];
        bf16x8 kf1 = *(const bf16x8*)&Ks[l31*K_PITCH + 16 + 8*hi];

        for (int ks = 0; ks < 11; ks++) {
            // this-iter R loads (consumed after QK MFMAs)
            f32x4 rA = *(const f32x4*)(Rrow + 32*ks);
            f32x4 rB = *(const f32x4*)(Rrow + 32*ks + 8);
            f32x4 rC = *(const f32x4*)(Rrow + 32*ks + 16);
            f32x4 rD = *(const f32x4*)(Rrow + 32*ks + 24);
            // prefetch K (LDS) for ks+1
            bf16x8 kf0n = kf0, kf1n = kf1;
            if (ks < 10) {
                int krn = min(32*(ks+1) + l31, NN-1);
                kf0n = *(const bf16x8*)&Ks[krn*K_PITCH + 8*hi];
                kf1n = *(const bf16x8*)&Ks[krn*K_PITCH + 16 + 8*hi];
            }

            f32x16 s = mfma32(kf0, qf0, zero16);
            s = mfma32(kf1, qf1, s);

            unsigned bits = (unsigned)(ma & 0xFFFFu);
            ma = (ma >> 16) | (mbq << 48); mbq = (mbq >> 16) | (mc << 48); mc >>= 16;

            float pv[16];
            #pragma unroll
            for (int r = 0; r < 4; r++) {
                pv[r]    = (bits & (1u << r))      ? __builtin_amdgcn_exp2f(s[r])    * rA[r] : 0.f;
                pv[4+r]  = (bits & (1u << (4+r)))  ? __builtin_amdgcn_exp2f(s[4+r])  * rB[r] : 0.f;
                pv[8+r]  = (bits & (1u << (8+r)))  ? __builtin_amdgcn_exp2f(s[8+r])  * rC[r] : 0.f;
                pv[12+r] = (bits & (1u << (12+r))) ? __builtin_amdgcn_exp2f(s[12+r]) * rD[r] : 0.f;
            }
            {
                float t0 = pv[0]+pv[1], t1 = pv[2]+pv[3], t2 = pv[4]+pv[5], t3 = pv[6]+pv[7];
                float t4 = pv[8]+pv[9], t5 = pv[10]+pv[11], t6 = pv[12]+pv[13], t7 = pv[14]+pv[15];
                dsum += ((t0+t1)+(t2+t3)) + ((t4+t5)+(t6+t7));
            }
            // pack + permlane redistribution (C layout -> A layout)
            unsigned w0 = pack2(pv[0],  pv[1]),  w1 = pack2(pv[2],  pv[3]);
            unsigned w2 = pack2(pv[4],  pv[5]),  w3 = pack2(pv[6],  pv[7]);
            unsigned w4 = pack2(pv[8],  pv[9]),  w5 = pack2(pv[10], pv[11]);
            unsigned w6 = pack2(pv[12], pv[13]), w7 = pack2(pv[14], pv[15]);
            pl32_swap(w0, w2); pl32_swap(w1, w3);
            pl32_swap(w4, w6); pl32_swap(w5, w7);
            union { unsigned u[4]; bf16x8 f; } fa, fb;
            fa.u[0] = w0; fa.u[1] = w1; fa.u[2] = w2; fa.u[3] = w3;   // m in [32ks, 32ks+16)
            fb.u[0] = w4; fb.u[1] = w5; fb.u[2] = w6; fb.u[3] = w7;   // m in [32ks+16, 32ks+32)

            bf16x8 v0 = *(const bf16x8*)&VTl[32*ks + 8*hi];
            bf16x8 v1 = *(const bf16x8*)&VTl[32*ks + 16 + 8*hi];
            O = mfma32(fa.f, v0, O);
            O = mfma32(fb.f, v1, O);

            kf0 = kf0n; kf1 = kf1n;
        }

        dsum += __shfl_xor(dsum, 32);
        float dinv = 1.f / dsum;

        #pragma unroll
        for (int r = 0; r < 16; r++) {
            int off = (r & 3) + 8*(r >> 2) + 4*hi;
            float dv = __shfl(dinv, off);
            int qr = q0 + off;
            if (qr < NN)
                cross[((size_t)b*NN + qr)*DIMC + 32*h + l31] = (__bf16)(O[r] * dv);
        }
    }
}

extern "C" void kernel_launch(void* const* d_in, const int* in_sizes, int n_in,
                              void* d_out, int out_size, void* d_ws, size_t ws_size,
                              hipStream_t stream) {
    const float* x           = (const float*)d_in[0];
    const float* y           = (const float*)d_in[1];
    const float* mask        = (const float*)d_in[2];
    const float* qkv1_w      = (const float*)d_in[3];
    const float* qkv2_w      = (const float*)d_in[4];
    const float* v1_bias     = (const float*)d_in[6];
    const float* q2_bias     = (const float*)d_in[7];
    const float* logit_scale = (const float*)d_in[9];
    const float* cpb_w1      = (const float*)d_in[10];
    const float* cpb_b1      = (const float*)d_in[11];
    const float* cpb_w2      = (const float*)d_in[12];
    const float* proj_w      = (const float*)d_in[13];
    const float* proj_b      = (const float*)d_in[14];
    const float* rel_table   = (const float*)d_in[15];
    const int*   rp_index    = (const int*)d_in[16];

    char* ws = (char*)d_ws;
    float*    table  = (float*)(ws + OFF_TABLE);
    float*    R      = (float*)(ws + OFF_R);
    unsigned* mb     = (unsigned*)(ws + OFF_MB);
    __bf16*   q_bf   = (__bf16*)(ws + OFF_QB);
    __bf16*   k_bf   = (__bf16*)(ws + OFF_KB);
    __bf16*   v_bf   = (__bf16*)(ws + OFF_VB);
    __bf16*   crossb = (__bf16*)(ws + OFF_CROSS);
    __bf16*   wbf    = (__bf16*)(ws + OFF_WB);

    __bf16* w_k    = wbf + 192*DIMC;        // qkv1 rows 192..383
    __bf16* w_v    = wbf + 384*DIMC;        // qkv1 rows 384..575
    __bf16* w_q    = wbf + 576*DIMC;        // qkv2 rows 0..191
    __bf16* w_proj = wbf + 1152*DIMC;

    cpb_table_kernel<<<2197, 256, 0, stream>>>(rel_table, cpb_w1, cpb_b1, cpb_w2, table);
    r_kernel<<<(HH*NN*352 + 255)/256, 256, 0, stream>>>(table, rp_index, R);
    mbits2_kernel<<<(64*NN*2 + 255)/256, 256, 0, stream>>>(mask, mb);
    wcvt_kernel<<<(258048/4 + 255)/256, 256, 0, stream>>>(qkv1_w, qkv2_w, proj_w, wbf);
    // x -> k (norm, no bias), v (+v1_bias, no norm)
    gemm_f32in<<<MM/64, 256, 0, stream>>>(x, logit_scale,
                                          w_k, nullptr, 1, k_bf,
                                          w_v, v1_bias, 0, v_bf);
    // y -> q (+q2_bias, norm+scale*log2e)
    gemm_f32in<<<MM/64, 256, 0, stream>>>(y, logit_scale,
                                          w_q, q2_bias, 2, q_bf,
                                          nullptr, nullptr, 0, nullptr);

    attn_kernel<<<BB*HH, 256, 0, stream>>>(q_bf, k_bf, v_bf, R, mb, crossb);

    gemm_proj<<<MM/64, 256, 0, stream>>>(crossb, w_proj, proj_b, (float*)d_out);
}